// Round 11
// baseline (154.688 us; speedup 1.0000x reference)
//
#include <hip/hip_runtime.h>

#define CC 192
#define NN 16384
#define TKB 128     // tokens per kproj block
#define CHS 32      // channels per K-chunk
#define LSTRIDE 130 // dwords per channel row in chunk buffer (128 + 2 pad)
#define QXST 104    // kq Xs stride (elems)
#define QST 200     // kq SsT stride (elems)

typedef unsigned short u16;
typedef __attribute__((ext_vector_type(4))) float f32x4;
typedef __attribute__((ext_vector_type(8))) __bf16 bf16x8;
typedef __attribute__((ext_vector_type(8))) u16 u16x8;
typedef __attribute__((ext_vector_type(4))) u16 u16x4;

union FragU { u16x8 u; bf16x8 b; };

__device__ __forceinline__ u16 f2bf(float f) {
  union { float f; unsigned u; } x; x.f = f;
  return (u16)((x.u + 0x7FFFu + ((x.u >> 16) & 1u)) >> 16);  // RNE
}
__device__ __forceinline__ float bf2f(u16 h) {
  union { unsigned u; float f; } x; x.u = ((unsigned)h) << 16;
  return x.f;
}

// width-4 global->LDS DMA: lane L contributes 4B at lds_base + 4L (linear).
__device__ __forceinline__ void gl_lds4(const float* g, float* l) {
  __builtin_amdgcn_global_load_lds(
      (const __attribute__((address_space(1))) void*)g,
      (__attribute__((address_space(3))) void*)l, 4, 0, 0);
}

// Issue one chunk's DMA: 32 ch x 128 tok fp32. Per wave 8 instrs (4 ch x 2 halves),
// each one 256-B linear request -> row = 2 adjacent 256-B requests (page-friendly).
__device__ __forceinline__ void dma_chunk(const float* __restrict__ xb, int c,
                                          int wv, int lane, float* buf) {
#pragma unroll
  for (int i = 0; i < 8; ++i) {
    const int chl = wv * 4 + (i >> 1);   // channel within chunk, 0..31
    const int half = i & 1;
    const float* src = xb + (size_t)(c * CHS + chl) * NN + half * 64 + lane;
    gl_lds4(src, &buf[chl * LSTRIDE + half * 64]);
  }
}

// K/V projection, pipelined fat block: 512 thr, 128 tok x 192 e, 6 K-chunks,
// DMA double-buffer with counted vmcnt (chunk c+1 flies over chunk c's MFMA).
// z=0: Sexp = exp(Wk@k+bk) + ksum atomics; z=1: Vbuf = Wv@v+bv.
__global__ __launch_bounds__(512, 2)
void kproj(const float* __restrict__ k, const float* __restrict__ v,
           const u16* __restrict__ Wb, const float* __restrict__ bk,
           const float* __restrict__ bv, u16* __restrict__ Sexp,
           u16* __restrict__ Vbuf, float* __restrict__ ksum)
{
  __shared__ __align__(16) float Xf[2][CHS * LSTRIDE];  // 2 x 16.6 KB

  const int b = blockIdx.y, pj = blockIdx.z;
  const int t0 = blockIdx.x * TKB;
  const int tid = threadIdx.x;
  const int wv = tid >> 6, lane = tid & 63;
  const int wr = wv >> 1, wc = wv & 1;       // e-quadrant / token-half
  const int lg = lane >> 4, lc = lane & 15;
  const int e0 = wr * 48;

  const float* xb = ((pj ? v : k) + (size_t)b * CC * NN) + t0;
  const u16* Wp = Wb + (pj ? 2 : 1) * 36864;
  const float* bias = pj ? bv : bk;
  u16* outp = pj ? Vbuf : Sexp;

  f32x4 acc[3][4];
#pragma unroll
  for (int et = 0; et < 3; ++et)
#pragma unroll
    for (int nt = 0; nt < 4; ++nt) acc[et][nt] = f32x4{0.f, 0.f, 0.f, 0.f};

  FragU w[2][3];

  // ---- prologue: DMA c0 -> buf0, W0, DMA c1 -> buf1  (queue: [d0 8][W0 3][d1 8]) ----
  dma_chunk(xb, 0, wv, lane, Xf[0]);
#pragma unroll
  for (int et = 0; et < 3; ++et)
    w[0][et].u = *reinterpret_cast<const u16x8*>(&Wp[(e0 + et * 16 + lc) * 192 + lg * 8]);
  dma_chunk(xb, 1, wv, lane, Xf[1]);

  // ---- 6 pipelined K-chunks ----
#pragma unroll
  for (int c = 0; c < 6; ++c) {
    // retire own chunk-c DMAs (+W_c); chunk c+1's 8 DMAs stay in flight
    if (c < 5) asm volatile("s_waitcnt vmcnt(8)" ::: "memory");
    else       asm volatile("s_waitcnt vmcnt(0)" ::: "memory");
    __builtin_amdgcn_s_barrier();           // all waves' chunk-c rows visible

    const float* buf = Xf[c & 1];
    // B-frags: fp32 LDS + cvt; stride 130 -> exactly 2 lanes/bank (free)
    FragU bb[4];
#pragma unroll
    for (int nt = 0; nt < 4; ++nt) {
      u16x8 f;
#pragma unroll
      for (int j = 0; j < 8; ++j)
        f[j] = f2bf(buf[(lg * 8 + j) * LSTRIDE + wc * 64 + nt * 16 + lc]);
      bb[nt].u = f;
    }
#pragma unroll
    for (int et = 0; et < 3; ++et)
#pragma unroll
      for (int nt = 0; nt < 4; ++nt)
        acc[et][nt] = __builtin_amdgcn_mfma_f32_16x16x32_bf16(w[c & 1][et].b, bb[nt].b,
                                                             acc[et][nt], 0, 0, 0);
    // next chunk's W-frags (keeps queue order [d_{c+1}][W_{c+1}][d_{c+2}])
    if (c < 5) {
#pragma unroll
      for (int et = 0; et < 3; ++et)
        w[(c + 1) & 1][et].u = *reinterpret_cast<const u16x8*>(
            &Wp[(e0 + et * 16 + lc) * 192 + (c + 1) * 32 + lg * 8]);
    }
    __builtin_amdgcn_s_barrier();           // all waves done reading buf[c&1]
    if (c < 4) dma_chunk(xb, c + 2, wv, lane, Xf[c & 1]);
  }

  // ---- epilogue: bias (+exp & ksum for K), bf16 stores ----
#pragma unroll
  for (int et = 0; et < 3; ++et)
#pragma unroll
    for (int r = 0; r < 4; ++r) {
      const int e = e0 + et * 16 + lg * 4 + r;
      const float bbv = bias[e];
      u16* orow = outp + (size_t)(b * 192 + e) * NN + t0 + wc * 64;
      if (!pj) {
        float sum = 0.f;
#pragma unroll
        for (int nt = 0; nt < 4; ++nt) {
          const float val = __expf(acc[et][nt][r] + bbv);   // |kp| small
          orow[nt * 16 + lc] = f2bf(val);
          sum += val;
        }
        sum += __shfl_xor(sum, 1);
        sum += __shfl_xor(sum, 2);
        sum += __shfl_xor(sum, 4);
        sum += __shfl_xor(sum, 8);
        if (lc == 0) atomicAdd(&ksum[b * 192 + e], sum);
      } else {
#pragma unroll
        for (int nt = 0; nt < 4; ++nt)
          orow[nt * 16 + lc] = f2bf(acc[et][nt][r] + bbv);
      }
    }
}

// ctx partials: block = (128-token slab, batch); 8 waves, wave = head. No LDS.
__global__ __launch_bounds__(512, 2)
void kctx(const u16* __restrict__ Sexp, const u16* __restrict__ Vbuf,
          float* __restrict__ part)
{
  const int b = blockIdx.y, slab = blockIdx.x;
  const int tid = threadIdx.x;
  const int h = tid >> 6;
  const int lg = (tid >> 4) & 3, lc = tid & 15;
  const int n0 = slab * 128;
  const size_t basee = (size_t)b * 192 * NN;

  f32x4 cacc[2][2];
#pragma unroll
  for (int mt = 0; mt < 2; ++mt)
#pragma unroll
    for (int nt = 0; nt < 2; ++nt) cacc[mt][nt] = f32x4{0.f, 0.f, 0.f, 0.f};

#pragma unroll
  for (int ks = 0; ks < 4; ++ks) {
    const int tok = n0 + ks * 32 + lg * 8;
    FragU av[2], bs[2];
#pragma unroll
    for (int mt = 0; mt < 2; ++mt) {
      int row = h * 24 + mt * 16 + lc;   // rows >= h*24+24 feed masked outputs
      if (row > 191) row = 191;
      av[mt].u = *reinterpret_cast<const u16x8*>(&Vbuf[basee + (size_t)row * NN + tok]);
      bs[mt].u = *reinterpret_cast<const u16x8*>(&Sexp[basee + (size_t)row * NN + tok]);
    }
#pragma unroll
    for (int mt = 0; mt < 2; ++mt)
#pragma unroll
      for (int nt = 0; nt < 2; ++nt)
        cacc[mt][nt] = __builtin_amdgcn_mfma_f32_16x16x32_bf16(
            av[mt].b, bs[nt].b, cacc[mt][nt], 0, 0, 0);
  }

  float* pp = part + (((size_t)(b * 128 + slab)) * 8 + h) * 576;
#pragma unroll
  for (int mt = 0; mt < 2; ++mt)
#pragma unroll
    for (int nt = 0; nt < 2; ++nt)
#pragma unroll
      for (int r = 0; r < 4; ++r) {
        const int dv = mt * 16 + lg * 4 + r;
        const int d = nt * 16 + lc;
        if (dv < 24 && d < 24) pp[dv * 24 + d] = cacc[mt][nt][r];
      }
}

// Reduce 128 slab partials + normalize by ksum (computed in kproj)
__global__ void kr2(const float* __restrict__ part, const float* __restrict__ ksum,
                    float* __restrict__ ctx)
{
  const int idx = blockIdx.x * 256 + threadIdx.x;
  if (idx >= 4608) return;
  const int b = blockIdx.y;
  const int h = idx / 576, rem = idx % 576;
  const int d = rem % 24;
  float s = 0.f;
  const float* pp = part + (size_t)b * 128 * 4608 + idx;
#pragma unroll 8
  for (int j = 0; j < 128; ++j) s += pp[(size_t)j * 4608];
  ctx[(size_t)b * 4608 + idx] = s / ksum[b * 192 + h * 24 + d];
}

// Meff[b][o][h*24+d] = sum_dv Wo[o][h*24+dv] * ctx[b][h][dv*24+d]
__global__ void km(const float* __restrict__ Wo, const float* __restrict__ ctx,
                   u16* __restrict__ Meff)
{
  const int o = blockIdx.x, b = blockIdx.y, j = threadIdx.x;
  const int h = j / 24, d = j % 24;
  const float* Wrow = Wo + o * 192 + h * 24;
  const float* crow = ctx + (size_t)b * 4608 + h * 576 + d;
  float acc = 0.f;
#pragma unroll
  for (int dv = 0; dv < 24; ++dv) acc += Wrow[dv] * crow[dv * 24];
  Meff[(b * 192 + o) * 192 + j] = f2bf(acc);
}

// One 192x192 (W) @ 192x64 (x fp32->bf16) GEMM (R7 version — empirically best kq).
__device__ __forceinline__ void gemm_stage_compute(
    const float* __restrict__ xb, const u16* __restrict__ Wp,
    int t0, int tid, f32x4 acc[3][4], u16 (*Xs)[QXST])
{
  const int lg = (tid >> 4) & 3, lc = tid & 15;
  const int wave = tid >> 6, e0 = wave * 48;
  const int sn = tid & 63, scg = tid >> 6;
#pragma unroll
  for (int et = 0; et < 3; ++et)
#pragma unroll
    for (int nt = 0; nt < 4; ++nt)
      acc[et][nt] = f32x4{0.f, 0.f, 0.f, 0.f};

#pragma unroll
  for (int hf = 0; hf < 2; ++hf) {
#pragma unroll
    for (int i = 0; i < 6; ++i) {
      int cl = scg * 4 + i * 16;
      const float* src = xb + (size_t)(hf * 96 + cl) * NN + t0 + sn;
      u16x4 p;
      p[0] = f2bf(src[0]);
      p[1] = f2bf(src[NN]);
      p[2] = f2bf(src[2 * NN]);
      p[3] = f2bf(src[3 * NN]);
      *reinterpret_cast<u16x4*>(&Xs[sn][cl]) = p;
    }
    __syncthreads();
#pragma unroll
    for (int ks = 0; ks < 3; ++ks) {
      FragU a[3], bb[4];
#pragma unroll
      for (int et = 0; et < 3; ++et)
        a[et].u = *reinterpret_cast<const u16x8*>(
            &Wp[(e0 + et * 16 + lc) * 192 + hf * 96 + ks * 32 + lg * 8]);
#pragma unroll
      for (int nt = 0; nt < 4; ++nt)
        bb[nt].u = *reinterpret_cast<const u16x8*>(&Xs[nt * 16 + lc][ks * 32 + lg * 8]);
#pragma unroll
      for (int et = 0; et < 3; ++et)
#pragma unroll
        for (int nt = 0; nt < 4; ++nt)
          acc[et][nt] = __builtin_amdgcn_mfma_f32_16x16x32_bf16(a[et].b, bb[nt].b,
                                                               acc[et][nt], 0, 0, 0);
    }
    __syncthreads();
  }
}

// Q kernel (R7 version): q-proj -> SsT[n][e] -> softmax over d -> Meff GEMM -> out.
__global__ __launch_bounds__(256, 4)
void kq(const float* __restrict__ q, const u16* __restrict__ Wb,
        const float* __restrict__ bq, const u16* __restrict__ Meff,
        const float* __restrict__ bo, float* __restrict__ out)
{
  __shared__ __align__(16) u16 Xs[64][QXST];
  __shared__ __align__(16) u16 SsT[64][QST];

  const int b = blockIdx.y;
  const int t0 = blockIdx.x * 64;
  const int tid = threadIdx.x;
  const int lg = (tid >> 4) & 3, lc = tid & 15;
  const int wave = tid >> 6, e0 = wave * 48;
  const u16* Mb = Meff + b * 36864;

  f32x4 acc[3][4];

  gemm_stage_compute(q + (size_t)b * CC * NN, Wb, t0, tid, acc, Xs);
#pragma unroll
  for (int et = 0; et < 3; ++et)
#pragma unroll
    for (int r = 0; r < 4; ++r) {
      int e = e0 + et * 16 + lg * 4 + r;
      float bias = bq[e];
#pragma unroll
      for (int nt = 0; nt < 4; ++nt)
        SsT[nt * 16 + lc][e] = f2bf(acc[et][nt][r] + bias);
    }
  __syncthreads();

#pragma unroll
  for (int ii = 0; ii < 2; ++ii) {
    const int item = ii * 256 + tid;
    const int n = item & 63, h = item >> 6;
    u16* rowp = &SsT[n][h * 24];
    float vals[24];
    float m = -1e30f;
#pragma unroll
    for (int d = 0; d < 24; ++d) {
      vals[d] = bf2f(rowp[d]);
      m = fmaxf(m, vals[d]);
    }
    float s = 0.f;
#pragma unroll
    for (int d = 0; d < 24; ++d) { vals[d] = __expf(vals[d] - m); s += vals[d]; }
    const float inv = 1.f / s;
#pragma unroll
    for (int d = 0; d < 24; ++d) rowp[d] = f2bf(vals[d] * inv);
  }
  __syncthreads();

#pragma unroll
  for (int et = 0; et < 3; ++et)
#pragma unroll
    for (int nt = 0; nt < 4; ++nt) acc[et][nt] = f32x4{0.f, 0.f, 0.f, 0.f};
#pragma unroll
  for (int ks = 0; ks < 6; ++ks) {
    FragU a[3], bb[4];
#pragma unroll
    for (int et = 0; et < 3; ++et)
      a[et].u = *reinterpret_cast<const u16x8*>(
          &Mb[(e0 + et * 16 + lc) * 192 + ks * 32 + lg * 8]);
#pragma unroll
    for (int nt = 0; nt < 4; ++nt)
      bb[nt].u = *reinterpret_cast<const u16x8*>(&SsT[nt * 16 + lc][ks * 32 + lg * 8]);
#pragma unroll
    for (int et = 0; et < 3; ++et)
#pragma unroll
      for (int nt = 0; nt < 4; ++nt)
        acc[et][nt] = __builtin_amdgcn_mfma_f32_16x16x32_bf16(a[et].b, bb[nt].b,
                                                             acc[et][nt], 0, 0, 0);
  }

#pragma unroll
  for (int et = 0; et < 3; ++et)
#pragma unroll
    for (int r = 0; r < 4; ++r) {
      int row = e0 + et * 16 + lg * 4 + r;
      float bias = bo[row];
#pragma unroll
      for (int nt = 0; nt < 4; ++nt)
        out[(size_t)(b * 192 + row) * NN + t0 + nt * 16 + lc] = acc[et][nt][r] + bias;
    }
}

// Convert Wq/Wk/Wv to bf16; zero ksum (768 floats).
__global__ void kz(const float* __restrict__ Wq, const float* __restrict__ Wk,
                   const float* __restrict__ Wv, u16* __restrict__ Wb,
                   float* __restrict__ ksum)
{
  const int i = blockIdx.x * 256 + threadIdx.x;
  if (i < 110592) {
    const float* src = (i < 36864) ? Wq : (i < 73728) ? Wk : Wv;
    Wb[i] = f2bf(src[i % 36864]);
  }
  if (i < 768) ksum[i] = 0.f;
}

extern "C" void kernel_launch(void* const* d_in, const int* in_sizes, int n_in,
                              void* d_out, int out_size, void* d_ws, size_t ws_size,
                              hipStream_t stream)
{
  const float* q  = (const float*)d_in[0];
  const float* k  = (const float*)d_in[1];
  const float* v  = (const float*)d_in[2];
  const float* Wq = (const float*)d_in[3];
  const float* bq = (const float*)d_in[4];
  const float* Wk = (const float*)d_in[5];
  const float* bk = (const float*)d_in[6];
  const float* Wv = (const float*)d_in[7];
  const float* bv = (const float*)d_in[8];
  const float* Wo = (const float*)d_in[9];
  const float* bo = (const float*)d_in[10];
  float* out = (float*)d_out;

  // workspace carve (256B-aligned); total ~60.4 MB
  char* w = (char*)d_ws;
  u16*   Wb   = (u16*)(w);                     // 221184 B
  u16*   Sexp = (u16*)(w + 221184);            // 25165824 B : [4][192][16384] bf16
  u16*   Vbuf = (u16*)(w + 25387008);          // 25165824 B
  float* part = (float*)(w + 50552832);        // 9437184 B : [4][128][8][576]
  float* ksum = (float*)(w + 59990016);        // 3072 B
  float* ctx  = (float*)(w + 59993088);        // 73728 B
  u16*   Meff = (u16*)(w + 60066816);          // 294912 B

  hipLaunchKernelGGL(kz, dim3(432), dim3(256), 0, stream, Wq, Wk, Wv, Wb, ksum);
  hipLaunchKernelGGL(kproj, dim3(128, 4, 2), dim3(512), 0, stream,
                     k, v, Wb, bk, bv, Sexp, Vbuf, ksum);
  hipLaunchKernelGGL(kctx, dim3(128, 4), dim3(512), 0, stream, Sexp, Vbuf, part);
  hipLaunchKernelGGL(kr2, dim3(18, 4), dim3(256), 0, stream, part, ksum, ctx);
  hipLaunchKernelGGL(km, dim3(192, 4), dim3(192), 0, stream, Wo, ctx, Meff);
  hipLaunchKernelGGL(kq, dim3(256, 4), dim3(256), 0, stream, q, Wb, bq, Meff, bo, out);
}

// Round 12
// 129.336 us; speedup vs baseline: 1.1960x; 1.1960x over previous
//
#include <hip/hip_runtime.h>

#define CC 192
#define NN 16384
#define XST 198   // staging stride (elems) = 99 dw (odd)
#define QXST 104  // kq Xs stride (elems)
#define QST 200   // kq SsT stride (elems)

typedef unsigned short u16;
typedef __attribute__((ext_vector_type(4))) float f32x4;
typedef __attribute__((ext_vector_type(8))) __bf16 bf16x8;
typedef __attribute__((ext_vector_type(8))) u16 u16x8;
typedef __attribute__((ext_vector_type(4))) u16 u16x4;

union FragU { u16x8 u; bf16x8 b; };

__device__ __forceinline__ u16 f2bf(float f) {
  union { float f; unsigned u; } x; x.f = f;
  return (u16)((x.u + 0x7FFFu + ((x.u >> 16) & 1u)) >> 16);  // RNE
}
__device__ __forceinline__ float bf2f(u16 h) {
  union { unsigned u; float f; } x; x.u = ((unsigned)h) << 16;
  return x.f;
}

// K/V projection: 64-token tile, 12 x f32x4 staging loads kept ALL in flight
// (launch_bounds(256,1) -> allocator free to hold p[12] = 48 VGPR), W-frags
// loaded per k-step inside the MFMA loop (L2-hot, latency hidden by MFMA).
// z=0: Sexp = exp(Wk@k+bk) + ksum atomics; z=1: Vbuf = Wv@v+bv.
__global__ __launch_bounds__(256, 1)
void kproj(const float* __restrict__ k, const float* __restrict__ v,
           const u16* __restrict__ Wb, const float* __restrict__ bk,
           const float* __restrict__ bv, u16* __restrict__ Sexp,
           u16* __restrict__ Vbuf, float* __restrict__ ksum)
{
  __shared__ __align__(16) u16 Xs[64][XST];    // 25.3 KB
  const int b = blockIdx.y, pj = blockIdx.z;
  const int t0 = blockIdx.x * 64;
  const int tid = threadIdx.x;
  const int lane = tid & 63, wave = tid >> 6;
  const int lg = lane >> 4, lc = lane & 15;
  const int e0 = wave * 48;
  const int tg = tid & 15, chq = tid >> 4;     // token-group / channel-quad

  const float* xb = (pj ? v : k) + (size_t)b * CC * NN;
  const u16* Wp = Wb + (pj ? 2 : 1) * 36864;
  const float* bias = pj ? bv : bk;
  u16* outp = pj ? Vbuf : Sexp;

  // ---- issue all 12 wide X loads; keep every one in flight ----
  f32x4 p[12];
#pragma unroll
  for (int i = 0; i < 12; ++i)
    p[i] = *reinterpret_cast<const f32x4*>(xb + (size_t)(i * 16 + chq) * NN + t0 + tg * 4);

  // ---- cvt + transposed LDS writes ----
#pragma unroll
  for (int i = 0; i < 12; ++i) {
    const int ch = i * 16 + chq;
    Xs[tg * 4 + 0][ch] = f2bf(p[i][0]);
    Xs[tg * 4 + 1][ch] = f2bf(p[i][1]);
    Xs[tg * 4 + 2][ch] = f2bf(p[i][2]);
    Xs[tg * 4 + 3][ch] = f2bf(p[i][3]);
  }
  __syncthreads();

  // ---- 6 MFMA k-steps; W frags loaded per step (hidden by MFMA) ----
  f32x4 acc[3][4];
#pragma unroll
  for (int et = 0; et < 3; ++et)
#pragma unroll
    for (int nt = 0; nt < 4; ++nt) acc[et][nt] = f32x4{0.f, 0.f, 0.f, 0.f};

#pragma unroll
  for (int ks = 0; ks < 6; ++ks) {
    FragU a[3], bb[4];
#pragma unroll
    for (int et = 0; et < 3; ++et)
      a[et].u = *reinterpret_cast<const u16x8*>(
          &Wp[(e0 + et * 16 + lc) * 192 + ks * 32 + lg * 8]);
#pragma unroll
    for (int nt = 0; nt < 4; ++nt)
      bb[nt].u = *reinterpret_cast<const u16x8*>(&Xs[nt * 16 + lc][ks * 32 + lg * 8]);
#pragma unroll
    for (int et = 0; et < 3; ++et)
#pragma unroll
      for (int nt = 0; nt < 4; ++nt)
        acc[et][nt] = __builtin_amdgcn_mfma_f32_16x16x32_bf16(a[et].b, bb[nt].b,
                                                             acc[et][nt], 0, 0, 0);
  }

  // ---- epilogue: bias (+exp & ksum for K), bf16 stores ----
#pragma unroll
  for (int et = 0; et < 3; ++et)
#pragma unroll
    for (int r = 0; r < 4; ++r) {
      const int e = e0 + et * 16 + lg * 4 + r;
      const float bbv = bias[e];
      u16* orow = outp + (size_t)(b * 192 + e) * NN + t0;
      if (!pj) {
        float sum = 0.f;
#pragma unroll
        for (int nt = 0; nt < 4; ++nt) {
          const float val = __expf(acc[et][nt][r] + bbv);   // |kp| small
          orow[nt * 16 + lc] = f2bf(val);
          sum += val;
        }
        sum += __shfl_xor(sum, 1);
        sum += __shfl_xor(sum, 2);
        sum += __shfl_xor(sum, 4);
        sum += __shfl_xor(sum, 8);
        if (lc == 0) atomicAdd(&ksum[b * 192 + e], sum);
      } else {
#pragma unroll
        for (int nt = 0; nt < 4; ++nt)
          orow[nt * 16 + lc] = f2bf(acc[et][nt][r] + bbv);
      }
    }
}

// ctx partials: block = (128-token slab, batch); 8 waves, wave = head. No LDS.
__global__ __launch_bounds__(512, 2)
void kctx(const u16* __restrict__ Sexp, const u16* __restrict__ Vbuf,
          float* __restrict__ part)
{
  const int b = blockIdx.y, slab = blockIdx.x;
  const int tid = threadIdx.x;
  const int h = tid >> 6;
  const int lg = (tid >> 4) & 3, lc = tid & 15;
  const int n0 = slab * 128;
  const size_t basee = (size_t)b * 192 * NN;

  f32x4 cacc[2][2];
#pragma unroll
  for (int mt = 0; mt < 2; ++mt)
#pragma unroll
    for (int nt = 0; nt < 2; ++nt) cacc[mt][nt] = f32x4{0.f, 0.f, 0.f, 0.f};

#pragma unroll
  for (int ks = 0; ks < 4; ++ks) {
    const int tok = n0 + ks * 32 + lg * 8;
    FragU av[2], bs[2];
#pragma unroll
    for (int mt = 0; mt < 2; ++mt) {
      int row = h * 24 + mt * 16 + lc;   // rows >= h*24+24 feed masked outputs
      if (row > 191) row = 191;
      av[mt].u = *reinterpret_cast<const u16x8*>(&Vbuf[basee + (size_t)row * NN + tok]);
      bs[mt].u = *reinterpret_cast<const u16x8*>(&Sexp[basee + (size_t)row * NN + tok]);
    }
#pragma unroll
    for (int mt = 0; mt < 2; ++mt)
#pragma unroll
      for (int nt = 0; nt < 2; ++nt)
        cacc[mt][nt] = __builtin_amdgcn_mfma_f32_16x16x32_bf16(
            av[mt].b, bs[nt].b, cacc[mt][nt], 0, 0, 0);
  }

  float* pp = part + (((size_t)(b * 128 + slab)) * 8 + h) * 576;
#pragma unroll
  for (int mt = 0; mt < 2; ++mt)
#pragma unroll
    for (int nt = 0; nt < 2; ++nt)
#pragma unroll
      for (int r = 0; r < 4; ++r) {
        const int dv = mt * 16 + lg * 4 + r;
        const int d = nt * 16 + lc;
        if (dv < 24 && d < 24) pp[dv * 24 + d] = cacc[mt][nt][r];
      }
}

// Reduce 128 slab partials + normalize by ksum (computed in kproj)
__global__ void kr2(const float* __restrict__ part, const float* __restrict__ ksum,
                    float* __restrict__ ctx)
{
  const int idx = blockIdx.x * 256 + threadIdx.x;
  if (idx >= 4608) return;
  const int b = blockIdx.y;
  const int h = idx / 576, rem = idx % 576;
  const int d = rem % 24;
  float s = 0.f;
  const float* pp = part + (size_t)b * 128 * 4608 + idx;
#pragma unroll 8
  for (int j = 0; j < 128; ++j) s += pp[(size_t)j * 4608];
  ctx[(size_t)b * 4608 + idx] = s / ksum[b * 192 + h * 24 + d];
}

// Meff[b][o][h*24+d] = sum_dv Wo[o][h*24+dv] * ctx[b][h][dv*24+d]
__global__ void km(const float* __restrict__ Wo, const float* __restrict__ ctx,
                   u16* __restrict__ Meff)
{
  const int o = blockIdx.x, b = blockIdx.y, j = threadIdx.x;
  const int h = j / 24, d = j % 24;
  const float* Wrow = Wo + o * 192 + h * 24;
  const float* crow = ctx + (size_t)b * 4608 + h * 576 + d;
  float acc = 0.f;
#pragma unroll
  for (int dv = 0; dv < 24; ++dv) acc += Wrow[dv] * crow[dv * 24];
  Meff[(b * 192 + o) * 192 + j] = f2bf(acc);
}

// One 192x192 (W) @ 192x64 (x fp32->bf16) GEMM (R7 version — empirically best kq).
__device__ __forceinline__ void gemm_stage_compute(
    const float* __restrict__ xb, const u16* __restrict__ Wp,
    int t0, int tid, f32x4 acc[3][4], u16 (*Xs)[QXST])
{
  const int lg = (tid >> 4) & 3, lc = tid & 15;
  const int wave = tid >> 6, e0 = wave * 48;
  const int sn = tid & 63, scg = tid >> 6;
#pragma unroll
  for (int et = 0; et < 3; ++et)
#pragma unroll
    for (int nt = 0; nt < 4; ++nt)
      acc[et][nt] = f32x4{0.f, 0.f, 0.f, 0.f};

#pragma unroll
  for (int hf = 0; hf < 2; ++hf) {
#pragma unroll
    for (int i = 0; i < 6; ++i) {
      int cl = scg * 4 + i * 16;
      const float* src = xb + (size_t)(hf * 96 + cl) * NN + t0 + sn;
      u16x4 p;
      p[0] = f2bf(src[0]);
      p[1] = f2bf(src[NN]);
      p[2] = f2bf(src[2 * NN]);
      p[3] = f2bf(src[3 * NN]);
      *reinterpret_cast<u16x4*>(&Xs[sn][cl]) = p;
    }
    __syncthreads();
#pragma unroll
    for (int ks = 0; ks < 3; ++ks) {
      FragU a[3], bb[4];
#pragma unroll
      for (int et = 0; et < 3; ++et)
        a[et].u = *reinterpret_cast<const u16x8*>(
            &Wp[(e0 + et * 16 + lc) * 192 + hf * 96 + ks * 32 + lg * 8]);
#pragma unroll
      for (int nt = 0; nt < 4; ++nt)
        bb[nt].u = *reinterpret_cast<const u16x8*>(&Xs[nt * 16 + lc][ks * 32 + lg * 8]);
#pragma unroll
      for (int et = 0; et < 3; ++et)
#pragma unroll
        for (int nt = 0; nt < 4; ++nt)
          acc[et][nt] = __builtin_amdgcn_mfma_f32_16x16x32_bf16(a[et].b, bb[nt].b,
                                                               acc[et][nt], 0, 0, 0);
    }
    __syncthreads();
  }
}

// Q kernel (R7 version): q-proj -> SsT[n][e] -> softmax over d -> Meff GEMM -> out.
__global__ __launch_bounds__(256, 2)
void kq(const float* __restrict__ q, const u16* __restrict__ Wb,
        const float* __restrict__ bq, const u16* __restrict__ Meff,
        const float* __restrict__ bo, float* __restrict__ out)
{
  __shared__ __align__(16) u16 Xs[64][QXST];
  __shared__ __align__(16) u16 SsT[64][QST];

  const int b = blockIdx.y;
  const int t0 = blockIdx.x * 64;
  const int tid = threadIdx.x;
  const int lg = (tid >> 4) & 3, lc = tid & 15;
  const int wave = tid >> 6, e0 = wave * 48;
  const u16* Mb = Meff + b * 36864;

  f32x4 acc[3][4];

  gemm_stage_compute(q + (size_t)b * CC * NN, Wb, t0, tid, acc, Xs);
#pragma unroll
  for (int et = 0; et < 3; ++et)
#pragma unroll
    for (int r = 0; r < 4; ++r) {
      int e = e0 + et * 16 + lg * 4 + r;
      float bias = bq[e];
#pragma unroll
      for (int nt = 0; nt < 4; ++nt)
        SsT[nt * 16 + lc][e] = f2bf(acc[et][nt][r] + bias);
    }
  __syncthreads();

#pragma unroll
  for (int ii = 0; ii < 2; ++ii) {
    const int item = ii * 256 + tid;
    const int n = item & 63, h = item >> 6;
    u16* rowp = &SsT[n][h * 24];
    float vals[24];
    float m = -1e30f;
#pragma unroll
    for (int d = 0; d < 24; ++d) {
      vals[d] = bf2f(rowp[d]);
      m = fmaxf(m, vals[d]);
    }
    float s = 0.f;
#pragma unroll
    for (int d = 0; d < 24; ++d) { vals[d] = __expf(vals[d] - m); s += vals[d]; }
    const float inv = 1.f / s;
#pragma unroll
    for (int d = 0; d < 24; ++d) rowp[d] = f2bf(vals[d] * inv);
  }
  __syncthreads();

#pragma unroll
  for (int et = 0; et < 3; ++et)
#pragma unroll
    for (int nt = 0; nt < 4; ++nt) acc[et][nt] = f32x4{0.f, 0.f, 0.f, 0.f};
#pragma unroll
  for (int ks = 0; ks < 6; ++ks) {
    FragU a[3], bb[4];
#pragma unroll
    for (int et = 0; et < 3; ++et)
      a[et].u = *reinterpret_cast<const u16x8*>(
          &Mb[(e0 + et * 16 + lc) * 192 + ks * 32 + lg * 8]);
#pragma unroll
    for (int nt = 0; nt < 4; ++nt)
      bb[nt].u = *reinterpret_cast<const u16x8*>(&SsT[nt * 16 + lc][ks * 32 + lg * 8]);
#pragma unroll
    for (int et = 0; et < 3; ++et)
#pragma unroll
      for (int nt = 0; nt < 4; ++nt)
        acc[et][nt] = __builtin_amdgcn_mfma_f32_16x16x32_bf16(a[et].b, bb[nt].b,
                                                             acc[et][nt], 0, 0, 0);
  }

#pragma unroll
  for (int et = 0; et < 3; ++et)
#pragma unroll
    for (int r = 0; r < 4; ++r) {
      int row = e0 + et * 16 + lg * 4 + r;
      float bias = bo[row];
#pragma unroll
      for (int nt = 0; nt < 4; ++nt)
        out[(size_t)(b * 192 + row) * NN + t0 + nt * 16 + lc] = acc[et][nt][r] + bias;
    }
}

// Convert Wq/Wk/Wv to bf16; zero ksum (768 floats).
__global__ void kz(const float* __restrict__ Wq, const float* __restrict__ Wk,
                   const float* __restrict__ Wv, u16* __restrict__ Wb,
                   float* __restrict__ ksum)
{
  const int i = blockIdx.x * 256 + threadIdx.x;
  if (i < 110592) {
    const float* src = (i < 36864) ? Wq : (i < 73728) ? Wk : Wv;
    Wb[i] = f2bf(src[i % 36864]);
  }
  if (i < 768) ksum[i] = 0.f;
}

extern "C" void kernel_launch(void* const* d_in, const int* in_sizes, int n_in,
                              void* d_out, int out_size, void* d_ws, size_t ws_size,
                              hipStream_t stream)
{
  const float* q  = (const float*)d_in[0];
  const float* k  = (const float*)d_in[1];
  const float* v  = (const float*)d_in[2];
  const float* Wq = (const float*)d_in[3];
  const float* bq = (const float*)d_in[4];
  const float* Wk = (const float*)d_in[5];
  const float* bk = (const float*)d_in[6];
  const float* Wv = (const float*)d_in[7];
  const float* bv = (const float*)d_in[8];
  const float* Wo = (const float*)d_in[9];
  const float* bo = (const float*)d_in[10];
  float* out = (float*)d_out;

  // workspace carve (256B-aligned); total ~60.4 MB
  char* w = (char*)d_ws;
  u16*   Wb   = (u16*)(w);                     // 221184 B
  u16*   Sexp = (u16*)(w + 221184);            // 25165824 B : [4][192][16384] bf16
  u16*   Vbuf = (u16*)(w + 25387008);          // 25165824 B
  float* part = (float*)(w + 50552832);        // 9437184 B : [4][128][8][576]
  float* ksum = (float*)(w + 59990016);        // 3072 B
  float* ctx  = (float*)(w + 59993088);        // 73728 B
  u16*   Meff = (u16*)(w + 60066816);          // 294912 B

  hipLaunchKernelGGL(kz, dim3(432), dim3(256), 0, stream, Wq, Wk, Wv, Wb, ksum);
  hipLaunchKernelGGL(kproj, dim3(256, 4, 2), dim3(256), 0, stream,
                     k, v, Wb, bk, bv, Sexp, Vbuf, ksum);
  hipLaunchKernelGGL(kctx, dim3(128, 4), dim3(512), 0, stream, Sexp, Vbuf, part);
  hipLaunchKernelGGL(kr2, dim3(18, 4), dim3(256), 0, stream, part, ksum, ctx);
  hipLaunchKernelGGL(km, dim3(192, 4), dim3(192), 0, stream, Wo, ctx, Meff);
  hipLaunchKernelGGL(kq, dim3(256, 4), dim3(256), 0, stream, q, Wb, bq, Meff, bo, out);
}